// Round 10
// baseline (31.148 us; speedup 1.0000x reference)
//
#include <hip/hip_runtime.h>
#include <hip/hip_bf16.h>

#define BS 32
#define NQ 300
#define NC 92
#define NT 50
#define Q_TOT (BS * NQ)   // 9600
#define T_TOT (BS * NT)   // 1600
#define QPB 8             // q-rows per block (9600 = 1200 * 8)
#define TPB 320           // threads per block = targets per block (1600 = 5*320)

// d_ws layout (floats):
//   probT [NC * Q_TOT]   transposed prob matrix (3.53 MB)
//   qcx/qcy/qhw/qhh/qar [5 * Q_TOT] SoA q-side tables
#define WS_PROBT 0
#define WS_QCX   (NC * Q_TOT)
#define WS_QCY   (WS_QCX + 1 * Q_TOT)
#define WS_QHW   (WS_QCX + 2 * Q_TOT)
#define WS_QHH   (WS_QCX + 3 * Q_TOT)
#define WS_QAR   (WS_QCX + 4 * Q_TOT)

// K1: one wave per query row. Writes softmax probs TRANSPOSED (probT[c][q])
// so K2's per-target class costs are contiguous along q. Also SoA box params.
__global__ __launch_bounds__(256) void prep_kernel(
    const float* __restrict__ logits,   // [Q_TOT, NC]
    const float* __restrict__ boxes,    // [Q_TOT, 4] cxcywh
    float* __restrict__ ws)
{
    const int row  = blockIdx.x * 4 + (threadIdx.x >> 6);
    const int lane = threadIdx.x & 63;

    const float* rp = logits + (size_t)row * NC;
    float x0 = (lane < NC)      ? rp[lane]      : -INFINITY;
    float x1 = (lane + 64 < NC) ? rp[lane + 64] : -INFINITY;

    float m = fmaxf(x0, x1);
    #pragma unroll
    for (int off = 1; off < 64; off <<= 1)
        m = fmaxf(m, __shfl_xor(m, off));

    const float e0 = __expf(x0 - m);    // exp(-inf - m) == 0 for pad lanes
    const float e1 = __expf(x1 - m);
    float s = e0 + e1;
    #pragma unroll
    for (int off = 1; off < 64; off <<= 1)
        s += __shfl_xor(s, off);

    const float inv = 1.0f / s;
    float* pt = ws + WS_PROBT;
    if (lane < NC)      pt[(size_t)lane * Q_TOT + row]        = e0 * inv;
    if (lane + 64 < NC) pt[(size_t)(lane + 64) * Q_TOT + row] = e1 * inv;

    if (lane == 0) {
        const float4 b = *reinterpret_cast<const float4*>(boxes + 4 * row);
        ws[WS_QCX + row] = b.x;
        ws[WS_QCY + row] = b.y;
        ws[WS_QHW + row] = 0.5f * b.z;
        ws[WS_QHH + row] = 0.5f * b.w;
        ws[WS_QAR + row] = b.z * b.w;
    }
}

// K2: thread = one target t, 8 q-rows. Class costs come from TWO contiguous
// dwordx4 loads (probT row lbl, cols q0..q0+7) hoisted before the loop —
// the per-element divergent gather is gone. Hot loop: ~24 VALU + 1 store.
__global__ __launch_bounds__(TPB) void cost_kernel(
    const int*   __restrict__ tgt_labels,   // [T_TOT]
    const float* __restrict__ tgt_boxes,    // [T_TOT, 4] cxcywh
    const float* __restrict__ ws,           // probT + SoA q tables
    float* __restrict__ out)                // [Q_TOT, T_TOT]
{
    const int tid = threadIdx.x;
    const int t   = blockIdx.x * TPB + tid;
    const int q0  = blockIdx.y * QPB;

    // t-side in registers.
    const float4 tb = *reinterpret_cast<const float4*>(tgt_boxes + 4 * t);
    const float tcx = tb.x, tcy = tb.y;
    const float thw = 0.5f * tb.z, thh = 0.5f * tb.w;
    const float tar = tb.z * tb.w;
    const int lbl = tgt_labels[t];

    // Class costs for all 8 q-rows: contiguous, 32B, aligned (q0 % 8 == 0).
    const float* pt = ws + WS_PROBT + (size_t)lbl * Q_TOT + q0;
    const float4 pa = *reinterpret_cast<const float4*>(pt);
    const float4 pb = *reinterpret_cast<const float4*>(pt + 4);
    const float p[8] = {pa.x, pa.y, pa.z, pa.w, pb.x, pb.y, pb.z, pb.w};

    const float* qcx_t = ws + WS_QCX;
    const float* qcy_t = ws + WS_QCY;
    const float* qhw_t = ws + WS_QHW;
    const float* qhh_t = ws + WS_QHH;
    const float* qar_t = ws + WS_QAR;
    float* op = out + (size_t)q0 * T_TOT + t;

    #pragma unroll
    for (int i = 0; i < QPB; ++i) {
        const int q = q0 + i;                    // block-uniform -> s_loads
        const float qcx = qcx_t[q], qcy = qcy_t[q];
        const float qhw = qhw_t[q], qhh = qhh_t[q];
        const float qar = qar_t[q];

        const float ux = qcx - tcx, uy = qcy - tcy;
        const float vx = qhw - thw, vy = qhh - thh;
        const float hx = qhw + thw, hy = qhh + thh;

        const float mx = fmaxf(fabsf(ux), fabsf(vx));   // abs = input mods
        const float my = fmaxf(fabsf(uy), fabsf(vy));
        const float dx = hx - mx, dy = hy - my;
        const float iw = fmaxf(dx, 0.0f), ih = fmaxf(dy, 0.0f);
        const float inter = iw * ih;
        const float ew = fmaf(2.0f, hx, -dx);    // enclosing = 2h - d
        const float eh = fmaf(2.0f, hy, -dy);
        const float earea = ew * eh;

        const float uni = (qar + tar) - inter;
        const float ue  = uni * earea;
        const float rc  = __builtin_amdgcn_rcpf(ue);
        float num = inter * earea - ue;
        num = fmaf(uni, uni, num);               // num = giou * ue

        // l1 = |ux|+2|vx| + |uy|+2|vy|  (abs input mods on fma)
        const float l1 = fmaf(2.0f, fabsf(vx), fabsf(ux))
                       + fmaf(2.0f, fabsf(vy), fabsf(uy));

        // res = l1 - p - giou = fma(-num, rc, l1 - p)
        op[i * T_TOT] = fmaf(-num, rc, l1 - p[i]);
    }
}

extern "C" void kernel_launch(void* const* d_in, const int* in_sizes, int n_in,
                              void* d_out, int out_size, void* d_ws, size_t ws_size,
                              hipStream_t stream) {
    const float* pred_logits = (const float*)d_in[0]; // [32,300,92]
    const float* pred_boxes  = (const float*)d_in[1]; // [32,300,4]
    const int*   tgt_labels  = (const int*)d_in[2];   // [32,50]
    const float* tgt_boxes   = (const float*)d_in[3]; // [32,50,4]
    float* out = (float*)d_out;                       // [32,300,1600]
    float* ws  = (float*)d_ws;                        // 3.72 MB used

    prep_kernel<<<Q_TOT / 4, 256, 0, stream>>>(pred_logits, pred_boxes, ws);

    dim3 grid(T_TOT / TPB, Q_TOT / QPB);              // (5, 1200)
    cost_kernel<<<grid, TPB, 0, stream>>>(tgt_labels, tgt_boxes, ws, out);
}

// Round 11
// 26.812 us; speedup vs baseline: 1.1617x; 1.1617x over previous
//
#include <hip/hip_runtime.h>
#include <hip/hip_bf16.h>

#define BS 32
#define NQ 300
#define NC 92
#define NT 50
#define Q_TOT (BS * NQ)   // 9600
#define T_TOT (BS * NT)   // 1600
#define QPB 8             // q-rows per block (9600 = 1200 * 8)
#define TPB 320           // threads per block = targets per block

typedef float f2 __attribute__((ext_vector_type(2)));

static __device__ __forceinline__ f2 fma2(f2 a, f2 b, f2 c) {
    return __builtin_elementwise_fma(a, b, c);
}
static __device__ __forceinline__ f2 max2(f2 a, f2 b) {
    return __builtin_elementwise_max(a, b);
}
static __device__ __forceinline__ f2 abs2(f2 a) {
    return __builtin_elementwise_abs(a);
}

// K1: one wave per query row. Computes softmax stats AND repacks the q-side
// into SoA tables so K2 can load (q, q+1) pairs as single 8B loads:
//   ws layout: qcx | qcy | qhw(=w/2) | qhh(=h/2) | qar | qm | qinv, each [Q_TOT]
__global__ __launch_bounds__(256) void prep_kernel(
    const float* __restrict__ logits,   // [Q_TOT, NC]
    const float* __restrict__ boxes,    // [Q_TOT, 4] cxcywh
    float* __restrict__ ws)
{
    const int row  = blockIdx.x * 4 + (threadIdx.x >> 6);
    const int lane = threadIdx.x & 63;

    const float* rp = logits + (size_t)row * NC;
    float x0 = (lane < NC)      ? rp[lane]      : -INFINITY;
    float x1 = (lane + 64 < NC) ? rp[lane + 64] : -INFINITY;

    float m = fmaxf(x0, x1);
    #pragma unroll
    for (int off = 1; off < 64; off <<= 1)
        m = fmaxf(m, __shfl_xor(m, off));

    float s = __expf(x0 - m) + __expf(x1 - m);   // exp(-inf - m) == 0
    #pragma unroll
    for (int off = 1; off < 64; off <<= 1)
        s += __shfl_xor(s, off);

    if (lane == 0) {
        const float4 b = *reinterpret_cast<const float4*>(boxes + 4 * row);
        ws[0 * Q_TOT + row] = b.x;               // qcx
        ws[1 * Q_TOT + row] = b.y;               // qcy
        ws[2 * Q_TOT + row] = 0.5f * b.z;        // qhw
        ws[3 * Q_TOT + row] = 0.5f * b.w;        // qhh
        ws[4 * Q_TOT + row] = b.z * b.w;         // qar
        ws[5 * Q_TOT + row] = m;                 // qm
        ws[6 * Q_TOT + row] = 1.0f / s;          // qinv
    }
}

// K2: thread = one target; 8 q-rows as 4 packed (q, q+1) f32-pairs.
// Per-dim identities (exact in real arithmetic):
//   dx  = (hwq+hwt) - max(|u|,|v|)   u = qcx-tcx, v = hwq-hwt   (pre-clamp inter width)
//   iw  = max(dx, 0)
//   ew  = 2*(hwq+hwt) - dx           (enclosing width, no min/max)
//   l1x = |u| + 2|v|                 (shares |u|,|v|)
__global__ __launch_bounds__(TPB) void cost_kernel_pk(
    const float* __restrict__ logits,       // [Q_TOT, NC]
    const int*   __restrict__ tgt_labels,   // [T_TOT]
    const float* __restrict__ tgt_boxes,    // [T_TOT, 4] cxcywh
    const float* __restrict__ ws,           // SoA q-tables (see K1)
    float* __restrict__ out)                // [Q_TOT, T_TOT]
{
    const float* qcx_t = ws + 0 * Q_TOT;
    const float* qcy_t = ws + 1 * Q_TOT;
    const float* qhw_t = ws + 2 * Q_TOT;
    const float* qhh_t = ws + 3 * Q_TOT;
    const float* qar_t = ws + 4 * Q_TOT;
    const float* qm_t  = ws + 5 * Q_TOT;
    const float* qiv_t = ws + 6 * Q_TOT;

    const int t  = blockIdx.x * TPB + threadIdx.x;
    const int q0 = blockIdx.y * QPB;

    // t-side, broadcast into both pk halves (hoisted once per thread)
    const float4 tb = *reinterpret_cast<const float4*>(tgt_boxes + 4 * t);
    const f2 tcx = {tb.x, tb.x};
    const f2 tcy = {tb.y, tb.y};
    const f2 thw = {0.5f * tb.z, 0.5f * tb.z};
    const f2 thh = {0.5f * tb.w, 0.5f * tb.w};
    const f2 tar = {tb.z * tb.w, tb.z * tb.w};
    const int lbl = tgt_labels[t];

    const float* lp = logits + (size_t)q0 * NC + lbl;  // per-thread gather base
    float* op = out + (size_t)q0 * T_TOT + t;
    const f2 two = {2.0f, 2.0f};
    const f2 zero = {0.0f, 0.0f};

    #pragma unroll
    for (int p = 0; p < QPB / 2; ++p) {
        const int q = q0 + 2 * p;

        // q-pair tables: single 8B loads (uniform address -> scalar loads)
        const f2 qcx = *reinterpret_cast<const f2*>(qcx_t + q);
        const f2 qcy = *reinterpret_cast<const f2*>(qcy_t + q);
        const f2 qhw = *reinterpret_cast<const f2*>(qhw_t + q);
        const f2 qhh = *reinterpret_cast<const f2*>(qhh_t + q);
        const f2 qar = *reinterpret_cast<const f2*>(qar_t + q);
        const f2 qm  = *reinterpret_cast<const f2*>(qm_t  + q);
        const f2 qiv = *reinterpret_cast<const f2*>(qiv_t + q);

        // class cost: 2 divergent gathers, compile-time offsets off one base
        const f2 lg = {lp[184 * p], lp[184 * p + NC]};

        const f2 ux = qcx - tcx,  uy = qcy - tcy;     // pk_sub
        const f2 vx = qhw - thw,  vy = qhh - thh;     // pk_sub
        const f2 hx = qhw + thw,  hy = qhh + thh;     // pk_add
        const f2 aux = abs2(ux), auy = abs2(uy);
        const f2 avx = abs2(vx), avy = abs2(vy);
        const f2 mx = max2(aux, avx), my = max2(auy, avy);
        const f2 dx = hx - mx, dy = hy - my;
        const f2 iw = max2(dx, zero), ih = max2(dy, zero);
        const f2 ew = fma2(two, hx, -dx);             // enclosing w = 2hs - dx
        const f2 eh = fma2(two, hy, -dy);

        const f2 inter = iw * ih;
        const f2 earea = ew * eh;
        const f2 uni   = (qar + tar) - inter;
        const f2 ue    = uni * earea;
        const f2 rc    = {__builtin_amdgcn_rcpf(ue.x), __builtin_amdgcn_rcpf(ue.y)};
        // giou = (inter*earea - ue + uni^2) * rcp(ue)
        const f2 giou  = fma2(uni, uni, inter * earea - ue) * rc;

        // l1 = |ux|+2|vx| + |uy|+2|vy|
        const f2 l1 = fma2(two, avx, aux) + fma2(two, avy, auy);

        // prob = exp(lg - m) * inv
        const f2 pe = lg - qm;
        f2 prob = {__expf(pe.x), __expf(pe.y)};
        prob *= qiv;

        const f2 res = l1 - prob - giou;
        op[3200 * p]        = res.x;   // row q   (coalesced along t)
        op[3200 * p + 1600] = res.y;   // row q+1
    }
}

extern "C" void kernel_launch(void* const* d_in, const int* in_sizes, int n_in,
                              void* d_out, int out_size, void* d_ws, size_t ws_size,
                              hipStream_t stream) {
    const float* pred_logits = (const float*)d_in[0]; // [32,300,92]
    const float* pred_boxes  = (const float*)d_in[1]; // [32,300,4]
    const int*   tgt_labels  = (const int*)d_in[2];   // [32,50]
    const float* tgt_boxes   = (const float*)d_in[3]; // [32,50,4]
    float* out = (float*)d_out;                       // [32,300,1600]
    float* ws  = (float*)d_ws;                        // 7 * 9600 f32 = 262.5 KB

    prep_kernel<<<Q_TOT / 4, 256, 0, stream>>>(pred_logits, pred_boxes, ws);

    dim3 grid(T_TOT / TPB, Q_TOT / QPB);              // (5, 1200)
    cost_kernel_pk<<<grid, TPB, 0, stream>>>(pred_logits, tgt_labels,
                                             tgt_boxes, ws, out);
}